// Round 14
// baseline (91.366 us; speedup 1.0000x reference)
//
#include <hip/hip_runtime.h>
#include <hip/hip_bf16.h>
#include <math.h>

// Problem constants (B,C,H,W) = (2,64,128,128), R=2 -> K=24 neighbors.
#define NNODES 16384            // H*W
#define KE 24

typedef float f32x4 __attribute__((ext_vector_type(4)));
typedef short bf16x8 __attribute__((ext_vector_type(8)));
typedef unsigned u32x4 __attribute__((ext_vector_type(4)));

union fragcast { u32x4 u; bf16x8 b; };

// Exact 3-way truncation split: v == hi + lo + lo2 (all bf16-representable).
static __device__ __forceinline__ void split3(float v, unsigned& uh,
                                              unsigned& ul, unsigned& um) {
    union { float f; unsigned u; } a; a.f = v;
    uh = a.u & 0xFFFF0000u;
    union { unsigned u; float f; } h; h.u = uh;
    float r1 = v - h.f;                      // exact
    union { float f; unsigned u; } b; b.f = r1;
    ul = b.u & 0xFFFF0000u;
    union { unsigned u; float f; } l; l.u = ul;
    float r2 = r1 - l.f;                     // exact, <= 8 sig bits
    union { float f; unsigned u; } c; c.f = r2;
    um = c.u;                                // top 16 bits == exact bf16
}

static __device__ __forceinline__ unsigned pack_hi16(unsigned even, unsigned odd) {
    return __builtin_amdgcn_perm(odd, even, 0x07060302u);   // v_perm_b32
}

// ---------------------------------------------------------------------------
// A: per-node precompute. 256 threads, thread tile 8h x 4n (unchanged, R13).
// ---------------------------------------------------------------------------
__global__ __launch_bounds__(256) void precompute_k(
    const float* __restrict__ x, const float* __restrict__ W1,
    const float* __restrict__ Wm, const float* __restrict__ b1,
    const float* __restrict__ bm,
    float* __restrict__ zsrc, float* __restrict__ ztgt, float* __restrict__ msg,
    float* __restrict__ zpos)
{
    __shared__ float xt[64][128];   // [c][node]  32 KB
    __shared__ float wl[64][64];    // [c][h]     16 KB
    const int t = threadIdx.x;
    const int mat = blockIdx.x >> 8;        // grid = 3*256
    const int tile = blockIdx.x & 255;
    const int n0 = tile * 128;
    const int b = n0 >> 14;
    const int nl0 = n0 & (NNODES - 1);
    const float* xb = x + (size_t)b * 64 * NNODES + nl0;

    if (blockIdx.x == 0) {                  // zpos table
        for (int idx = t; idx < KE * 64; idx += 256) {
            int k = idx >> 6, h = idx & 63;
            int kk = k + (k >= 12 ? 1 : 0);
            int q5 = (kk * 52) >> 8;
            int dy = q5 - 2, dx = kk - 5 * q5 - 2;
            zpos[idx] = W1[h * 130 + 128] * (dx * 0.5f)
                      + W1[h * 130 + 129] * (dy * 0.5f);
        }
    }

    #pragma unroll
    for (int r = 0; r < 8; ++r) {
        int idx = r * 256 + t;              // 2048 float4s
        int c = idx >> 5, j4 = idx & 31;
        float4 v = *(const float4*)(xb + (size_t)c * NNODES + j4 * 4);
        *(float4*)&xt[c][j4 * 4] = v;
    }
    #pragma unroll
    for (int r = 0; r < 16; ++r) {
        int idx = r * 256 + t;              // 4096 scalars
        int c = idx >> 6, h = idx & 63;
        float v = (mat == 0) ? W1[h * 130 + c]
                : (mat == 1) ? W1[h * 130 + 64 + c]
                             : Wm[h * 64 + c];
        (&wl[0][0])[idx] = v;
    }
    __syncthreads();

    const int i = t >> 5;   // h-octet (8 groups)
    const int j = t & 31;   // node-quad (32 groups)

    float acc[8][4];
    #pragma unroll
    for (int a = 0; a < 8; ++a)
        #pragma unroll
        for (int bb = 0; bb < 4; ++bb) acc[a][bb] = 0.f;

    #pragma unroll 4
    for (int c = 0; c < 64; ++c) {
        float4 w0 = *(const float4*)&wl[c][i * 8];
        float4 w1 = *(const float4*)&wl[c][i * 8 + 4];
        float4 x0 = *(const float4*)&xt[c][j * 4];
        float wv[8] = {w0.x, w0.y, w0.z, w0.w, w1.x, w1.y, w1.z, w1.w};
        float xv[4] = {x0.x, x0.y, x0.z, x0.w};
        #pragma unroll
        for (int a = 0; a < 8; ++a)
            #pragma unroll
            for (int bb = 0; bb < 4; ++bb)
                acc[a][bb] = fmaf(wv[a], xv[bb], acc[a][bb]);
    }

    #pragma unroll
    for (int a = 0; a < 8; ++a) {
        float bv = (mat == 0) ? b1[i * 8 + a] : (mat == 2) ? bm[i * 8 + a] : 0.f;
        #pragma unroll
        for (int bb = 0; bb < 4; ++bb) {
            float v = acc[a][bb] + bv;
            acc[a][bb] = (mat == 2) ? fmaxf(v, 0.f) : v;
        }
    }

    float* dst = (mat == 0) ? zsrc : (mat == 1) ? ztgt : msg;
    #pragma unroll
    for (int bb = 0; bb < 4; ++bb) {
        float* o = dst + (size_t)(n0 + j * 4 + bb) * 64 + i * 8;
        *(float4*)o       = make_float4(acc[0][bb], acc[1][bb], acc[2][bb], acc[3][bb]);
        *(float4*)(o + 4) = make_float4(acc[4][bb], acc[5][bb], acc[6][bb], acc[7][bb]);
    }
}

// ---------------------------------------------------------------------------
// B: scorer. Exact 3-way-split bf16 MFMA. Block = 16 row-aligned nodes;
//    ztgt neighborhood (5x20 node window) staged into LDS once (coalesced,
//    clamp baked in) -> per-Mt gather becomes LDS reads, no L2 round trip.
// ---------------------------------------------------------------------------
__global__ __launch_bounds__(256, 4) void score_k(
    const float* __restrict__ zsrc, const float* __restrict__ ztgt,
    const float* __restrict__ zpos, const float* __restrict__ W2,
    const float* __restrict__ b2, const float* __restrict__ W3,
    const float* __restrict__ b3, float* __restrict__ scores)
{
    __shared__ fragcast fraglds[64 * 13];   // 13 KB, lane-major stride 13
    __shared__ float zpl[24 * 68];          // 6.5 KB, padded rows
    __shared__ float ztile[100 * 68];       // 27.2 KB: 5x20 node window, pad 68

    const int t = threadIdx.x;
    const int l = t & 63;
    const int lcol = l & 15;
    const int lgrp = l >> 4;
    const int w = t >> 6;
    const int blkbase = blockIdx.x * 16;    // 16 consecutive nodes, same row
    const int b = blkbase >> 14;
    const int y = (blkbase >> 7) & 127;
    const int x0 = blkbase & 127;

    // stage zpos (coalesced)
    #pragma unroll
    for (int r = 0; r < 6; ++r) {
        int idx = r * 256 + t;
        zpl[(idx >> 6) * 68 + (idx & 63)] = zpos[idx];
    }
    // stage ztgt neighborhood window: rows (y-2..y+2) x cols (x0-2..x0+17),
    // clamped at borders; 100 rows x 64 floats, coalesced float4 loads.
    for (int i = t; i < 1600; i += 256) {
        int row = i >> 4, f4 = i & 15;
        int wy = (row * 3277) >> 16;        // row / 20 for row < 100
        int cx = row - wy * 20;
        int gy = min(max(y + wy - 2, 0), 127);
        int gx = min(max(x0 + cx - 2, 0), 127);
        int gn = (b << 14) + (gy << 7) + gx;
        *(float4*)&ztile[row * 68 + f4 * 4] =
            *(const float4*)(ztgt + (size_t)gn * 64 + f4 * 4);
    }
    // W2 fragments: wave w builds quadrant (jt = w>>1, kt = w&1)
    {
        const int jt = w >> 1, kt = w & 1;
        fragcast fh, fl, fl2;
        const float* wr = W2 + (size_t)(jt * 16 + lcol) * 64 + kt * 32 + lgrp * 8;
        #pragma unroll
        for (int d = 0; d < 4; ++d) {
            unsigned h0, l0, m0, h1, l1, m1;
            split3(wr[2 * d],     h0, l0, m0);
            split3(wr[2 * d + 1], h1, l1, m1);
            fh.u[d]  = pack_hi16(h0, h1);
            fl.u[d]  = pack_hi16(l0, l1);
            fl2.u[d] = pack_hi16(m0, m1);
        }
        fraglds[l * 13 + 0 + jt * 2 + kt] = fh;
        fraglds[l * 13 + 4 + jt * 2 + kt] = fl;
        fraglds[l * 13 + 8 + jt * 2 + kt] = fl2;
    }
    __syncthreads();

    const fragcast* fb = &fraglds[l * 13];
    const f32x4 b2l0 = *(const f32x4*)(b2 + lgrp * 4);
    const f32x4 b2l1 = *(const f32x4*)(b2 + 16 + lgrp * 4);
    const f32x4 w3l0 = *(const f32x4*)(W3 + lgrp * 4);
    const f32x4 w3l1 = *(const f32x4*)(W3 + 16 + lgrp * 4);
    const float b3s = b3[0];

    #pragma unroll 1
    for (int p = 0; p < 2; ++p) {
        const int node0 = blkbase + w * 4 + p * 2;

        #pragma unroll
        for (int Mt = 0; Mt < 3; ++Mt) {
            const int ke = Mt * 16 + lcol;
            const int nsel = (ke >= 24) ? 1 : 0;
            const int node = node0 + nsel;
            const int k = ke - 24 * nsel;
            const int xloc = (node & 127) - x0;          // 0..15
            const int kk = k + (k >= 12 ? 1 : 0);
            const int q5 = (kk * 52) >> 8;
            const int dy = q5 - 2, dx = kk - 5 * q5 - 2;
            const int trow = (dy + 2) * 20 + xloc + dx + 2;

            const float* zs = zsrc + (size_t)node * 64 + lgrp * 8;
            const float* zt = &ztile[trow * 68 + lgrp * 8];
            const float* zp = &zpl[k * 68 + lgrp * 8];

            f32x4 ac0A = {0.f,0.f,0.f,0.f}, ac0B = {0.f,0.f,0.f,0.f};
            f32x4 ac1A = {0.f,0.f,0.f,0.f}, ac1B = {0.f,0.f,0.f,0.f};

            #pragma unroll
            for (int kt = 0; kt < 2; ++kt) {
                const int o = kt * 32;
                float4 a0 = *(const float4*)(zs + o);
                float4 a1 = *(const float4*)(zs + o + 4);
                float4 t0 = *(const float4*)(zt + o);
                float4 t1 = *(const float4*)(zt + o + 4);
                float4 p0 = *(const float4*)(zp + o);
                float4 p1 = *(const float4*)(zp + o + 4);
                float v[8];
                v[0] = fmaxf(a0.x + t0.x + p0.x, 0.f);
                v[1] = fmaxf(a0.y + t0.y + p0.y, 0.f);
                v[2] = fmaxf(a0.z + t0.z + p0.z, 0.f);
                v[3] = fmaxf(a0.w + t0.w + p0.w, 0.f);
                v[4] = fmaxf(a1.x + t1.x + p1.x, 0.f);
                v[5] = fmaxf(a1.y + t1.y + p1.y, 0.f);
                v[6] = fmaxf(a1.z + t1.z + p1.z, 0.f);
                v[7] = fmaxf(a1.w + t1.w + p1.w, 0.f);

                fragcast Bh, Bl, Bl2;
                #pragma unroll
                for (int d = 0; d < 4; ++d) {
                    unsigned h0, l0, m0, h1, l1, m1;
                    split3(v[2 * d],     h0, l0, m0);
                    split3(v[2 * d + 1], h1, l1, m1);
                    Bh.u[d]  = pack_hi16(h0, h1);
                    Bl.u[d]  = pack_hi16(l0, l1);
                    Bl2.u[d] = pack_hi16(m0, m1);
                }

                ac0A = __builtin_amdgcn_mfma_f32_16x16x32_bf16(fb[0 + kt].b,  Bh.b,  ac0A, 0, 0, 0);
                ac1A = __builtin_amdgcn_mfma_f32_16x16x32_bf16(fb[2 + kt].b,  Bh.b,  ac1A, 0, 0, 0);
                ac0B = __builtin_amdgcn_mfma_f32_16x16x32_bf16(fb[4 + kt].b,  Bh.b,  ac0B, 0, 0, 0);
                ac1B = __builtin_amdgcn_mfma_f32_16x16x32_bf16(fb[6 + kt].b,  Bh.b,  ac1B, 0, 0, 0);
                ac0A = __builtin_amdgcn_mfma_f32_16x16x32_bf16(fb[8 + kt].b,  Bh.b,  ac0A, 0, 0, 0);
                ac1A = __builtin_amdgcn_mfma_f32_16x16x32_bf16(fb[10 + kt].b, Bh.b,  ac1A, 0, 0, 0);
                ac0B = __builtin_amdgcn_mfma_f32_16x16x32_bf16(fb[0 + kt].b,  Bl.b,  ac0B, 0, 0, 0);
                ac1B = __builtin_amdgcn_mfma_f32_16x16x32_bf16(fb[2 + kt].b,  Bl.b,  ac1B, 0, 0, 0);
                ac0A = __builtin_amdgcn_mfma_f32_16x16x32_bf16(fb[4 + kt].b,  Bl.b,  ac0A, 0, 0, 0);
                ac1A = __builtin_amdgcn_mfma_f32_16x16x32_bf16(fb[6 + kt].b,  Bl.b,  ac1A, 0, 0, 0);
                ac0B = __builtin_amdgcn_mfma_f32_16x16x32_bf16(fb[0 + kt].b,  Bl2.b, ac0B, 0, 0, 0);
                ac1B = __builtin_amdgcn_mfma_f32_16x16x32_bf16(fb[2 + kt].b,  Bl2.b, ac1B, 0, 0, 0);
            }

            const f32x4 s0 = ac0A + ac0B;
            const f32x4 s1 = ac1A + ac1B;
            float sacc = 0.f;
            #pragma unroll
            for (int q = 0; q < 4; ++q) {
                sacc = fmaf(fmaxf(s0[q] + b2l0[q], 0.f), w3l0[q], sacc);
                sacc = fmaf(fmaxf(s1[q] + b2l1[q], 0.f), w3l1[q], sacc);
            }
            sacc += __shfl_xor(sacc, 16);
            sacc += __shfl_xor(sacc, 32);
            float sig = 1.f / (1.f + expf(-(sacc + b3s)));
            if (l < 16)
                scores[(size_t)node0 * 24 + Mt * 16 + l] = sig;
        }
    }
}

// ---------------------------------------------------------------------------
// C: per-node rank/mask/weights + weighted msg aggregation + Wo + residual.
// ---------------------------------------------------------------------------
__global__ __launch_bounds__(256) void agg_k(
    const float* __restrict__ x, const float* __restrict__ scores,
    const float* __restrict__ msg, const float* __restrict__ Wo,
    const float* __restrict__ bo, const float* __restrict__ thrp,
    float* __restrict__ out)
{
    __shared__ float sc[768];
    __shared__ float wl[768];
    __shared__ float sumw[32];
    __shared__ float aggL[32][64];
    __shared__ float ot[64][33];

    const int t = threadIdx.x;
    const int n0 = blockIdx.x * 32;
    const int b = n0 >> 14;
    const int nl0 = n0 & (NNODES - 1);
    const float thr_v = 1.f / (1.f + expf(-thrp[0]));

    #pragma unroll
    for (int rep = 0; rep < 3; ++rep)
        sc[rep * 256 + t] = scores[(size_t)n0 * 24 + rep * 256 + t];
    __syncthreads();

    #pragma unroll
    for (int rep = 0; rep < 3; ++rep) {
        int e = rep * 256 + t;
        int nl = (int)(((unsigned)(e >> 3) * 171u) >> 9);   // e/24 for e<768
        int k = e - nl * 24;
        float s_e = sc[e];
        int rank = 0, cnt = 0;
        #pragma unroll
        for (int j = 0; j < 24; ++j) {
            float sj = sc[nl * 24 + j];
            rank += (sj > s_e || (sj == s_e && j < k)) ? 1 : 0;
            cnt  += (sj >= thr_v) ? 1 : 0;
        }
        bool mask = (cnt > 8) ? (rank < 8)
                  : ((cnt < 3) ? (rank < 3) : (s_e >= thr_v));
        float keep = 1.f / (1.f + expf(-(s_e - thr_v) * 10.f));
        wl[e] = mask ? s_e * keep : 0.f;
    }
    __syncthreads();

    if (t < 32) {
        float s = 0.f;
        #pragma unroll
        for (int k = 0; k < 24; ++k) s += wl[t * 24 + k];
        sumw[t] = s + 1e-6f;
    }
    __syncthreads();

    const int lane = t & 63;
    const int g4 = t >> 6;

    #pragma unroll
    for (int it = 0; it < 8; ++it) {
        int nl = g4 + it * 4;
        int nn = nl0 + nl;
        int yy = nn >> 7, xx = nn & 127;
        float acc = 0.f;
        #pragma unroll
        for (int k = 0; k < 24; ++k) {
            int kk = k + (k >= 12 ? 1 : 0);
            int q5 = (kk * 52) >> 8;
            int dy = q5 - 2, dx = kk - 5 * q5 - 2;
            int ny = min(max(yy + dy, 0), 127);
            int nx = min(max(xx + dx, 0), 127);
            int nb = (b << 14) + (ny << 7) + nx;
            acc = fmaf(wl[nl * 24 + k], msg[(size_t)nb * 64 + lane], acc);
        }
        aggL[nl][lane] = acc / sumw[nl];
    }

    float4 wo[16];
    #pragma unroll
    for (int c4 = 0; c4 < 16; ++c4) wo[c4] = ((const float4*)Wo)[lane * 16 + c4];
    __syncthreads();

    #pragma unroll
    for (int it = 0; it < 8; ++it) {
        int nl = g4 + it * 4;
        const float4* ar = (const float4*)aggL[nl];
        float a0 = 0.f, a1 = 0.f, a2 = 0.f, a3 = 0.f;
        #pragma unroll
        for (int c4 = 0; c4 < 16; ++c4) {
            float4 wv = wo[c4];
            float4 av = ar[c4];
            a0 = fmaf(av.x, wv.x, a0);
            a1 = fmaf(av.y, wv.y, a1);
            a2 = fmaf(av.z, wv.z, a2);
            a3 = fmaf(av.w, wv.w, a3);
        }
        float v = (a0 + a1) + (a2 + a3) + bo[lane]
                + x[(size_t)b * 64 * NNODES + (size_t)lane * NNODES + nl0 + nl];
        ot[lane][nl] = v;
    }
    __syncthreads();

    #pragma unroll
    for (int rep = 0; rep < 2; ++rep) {
        int idx = rep * 256 + t;
        int o = idx >> 3, p = idx & 7;
        float4 v = make_float4(ot[o][4 * p + 0], ot[o][4 * p + 1],
                               ot[o][4 * p + 2], ot[o][4 * p + 3]);
        *(float4*)(out + (size_t)b * 64 * NNODES + (size_t)o * NNODES + nl0 + 4 * p) = v;
    }
}

// ---------------------------------------------------------------------------
extern "C" void kernel_launch(void* const* d_in, const int* in_sizes, int n_in,
                              void* d_out, int out_size, void* d_ws, size_t ws_size,
                              hipStream_t stream)
{
    const float* x   = (const float*)d_in[0];
    const float* W1  = (const float*)d_in[1];
    const float* b1  = (const float*)d_in[2];
    const float* W2  = (const float*)d_in[3];
    const float* b2  = (const float*)d_in[4];
    const float* W3  = (const float*)d_in[5];
    const float* b3  = (const float*)d_in[6];
    const float* thr = (const float*)d_in[7];
    const float* Wm  = (const float*)d_in[8];
    const float* bm  = (const float*)d_in[9];
    const float* Wo  = (const float*)d_in[10];
    const float* bo  = (const float*)d_in[11];
    float* out = (float*)d_out;
    float* ws  = (float*)d_ws;

    // ws layout (floats): zsrc[2M] ztgt[2M] msg[2M] scores[768K] zpos[1536]
    float* zsrc   = ws;
    float* ztgt   = ws + 2097152;
    float* msg    = ws + 4194304;
    float* scores = ws + 6291456;
    float* zpos   = ws + 7077888;

    hipLaunchKernelGGL(precompute_k, dim3(768), dim3(256), 0, stream,
                       x, W1, Wm, b1, bm, zsrc, ztgt, msg, zpos);
    hipLaunchKernelGGL(score_k, dim3(2048), dim3(256), 0, stream,
                       zsrc, ztgt, zpos, W2, b2, W3, b3, scores);
    hipLaunchKernelGGL(agg_k, dim3(1024), dim3(256), 0, stream,
                       x, scores, msg, Wo, bo, thr, out);
}

// Round 15
// 89.383 us; speedup vs baseline: 1.0222x; 1.0222x over previous
//
#include <hip/hip_runtime.h>
#include <hip/hip_bf16.h>
#include <math.h>

// Problem constants (B,C,H,W) = (2,64,128,128), R=2 -> K=24 neighbors.
#define NNODES 16384            // H*W
#define KE 24

typedef float f32x4 __attribute__((ext_vector_type(4)));
typedef short bf16x8 __attribute__((ext_vector_type(8)));
typedef unsigned u32x4 __attribute__((ext_vector_type(4)));

union fragcast { u32x4 u; bf16x8 b; };

// Exact 3-way truncation split: v == hi + lo + lo2 (all bf16-representable).
static __device__ __forceinline__ void split3(float v, unsigned& uh,
                                              unsigned& ul, unsigned& um) {
    union { float f; unsigned u; } a; a.f = v;
    uh = a.u & 0xFFFF0000u;
    union { unsigned u; float f; } h; h.u = uh;
    float r1 = v - h.f;                      // exact
    union { float f; unsigned u; } b; b.f = r1;
    ul = b.u & 0xFFFF0000u;
    union { unsigned u; float f; } l; l.u = ul;
    float r2 = r1 - l.f;                     // exact, <= 8 sig bits
    union { float f; unsigned u; } c; c.f = r2;
    um = c.u;                                // top 16 bits == exact bf16
}

static __device__ __forceinline__ unsigned pack_hi16(unsigned even, unsigned odd) {
    return __builtin_amdgcn_perm(odd, even, 0x07060302u);   // v_perm_b32
}

// ---------------------------------------------------------------------------
// A: per-node precompute. 256 threads, thread tile 8h x 4n (unchanged).
// ---------------------------------------------------------------------------
__global__ __launch_bounds__(256) void precompute_k(
    const float* __restrict__ x, const float* __restrict__ W1,
    const float* __restrict__ Wm, const float* __restrict__ b1,
    const float* __restrict__ bm,
    float* __restrict__ zsrc, float* __restrict__ ztgt, float* __restrict__ msg,
    float* __restrict__ zpos)
{
    __shared__ float xt[64][128];   // [c][node]  32 KB
    __shared__ float wl[64][64];    // [c][h]     16 KB
    const int t = threadIdx.x;
    const int mat = blockIdx.x >> 8;        // grid = 3*256
    const int tile = blockIdx.x & 255;
    const int n0 = tile * 128;
    const int b = n0 >> 14;
    const int nl0 = n0 & (NNODES - 1);
    const float* xb = x + (size_t)b * 64 * NNODES + nl0;

    if (blockIdx.x == 0) {                  // zpos table
        for (int idx = t; idx < KE * 64; idx += 256) {
            int k = idx >> 6, h = idx & 63;
            int kk = k + (k >= 12 ? 1 : 0);
            int q5 = (kk * 52) >> 8;
            int dy = q5 - 2, dx = kk - 5 * q5 - 2;
            zpos[idx] = W1[h * 130 + 128] * (dx * 0.5f)
                      + W1[h * 130 + 129] * (dy * 0.5f);
        }
    }

    #pragma unroll
    for (int r = 0; r < 8; ++r) {
        int idx = r * 256 + t;              // 2048 float4s
        int c = idx >> 5, j4 = idx & 31;
        float4 v = *(const float4*)(xb + (size_t)c * NNODES + j4 * 4);
        *(float4*)&xt[c][j4 * 4] = v;
    }
    #pragma unroll
    for (int r = 0; r < 16; ++r) {
        int idx = r * 256 + t;              // 4096 scalars
        int c = idx >> 6, h = idx & 63;
        float v = (mat == 0) ? W1[h * 130 + c]
                : (mat == 1) ? W1[h * 130 + 64 + c]
                             : Wm[h * 64 + c];
        (&wl[0][0])[idx] = v;
    }
    __syncthreads();

    const int i = t >> 5;   // h-octet (8 groups)
    const int j = t & 31;   // node-quad (32 groups)

    float acc[8][4];
    #pragma unroll
    for (int a = 0; a < 8; ++a)
        #pragma unroll
        for (int bb = 0; bb < 4; ++bb) acc[a][bb] = 0.f;

    #pragma unroll 4
    for (int c = 0; c < 64; ++c) {
        float4 w0 = *(const float4*)&wl[c][i * 8];
        float4 w1 = *(const float4*)&wl[c][i * 8 + 4];
        float4 x0 = *(const float4*)&xt[c][j * 4];
        float wv[8] = {w0.x, w0.y, w0.z, w0.w, w1.x, w1.y, w1.z, w1.w};
        float xv[4] = {x0.x, x0.y, x0.z, x0.w};
        #pragma unroll
        for (int a = 0; a < 8; ++a)
            #pragma unroll
            for (int bb = 0; bb < 4; ++bb)
                acc[a][bb] = fmaf(wv[a], xv[bb], acc[a][bb]);
    }

    #pragma unroll
    for (int a = 0; a < 8; ++a) {
        float bv = (mat == 0) ? b1[i * 8 + a] : (mat == 2) ? bm[i * 8 + a] : 0.f;
        #pragma unroll
        for (int bb = 0; bb < 4; ++bb) {
            float v = acc[a][bb] + bv;
            acc[a][bb] = (mat == 2) ? fmaxf(v, 0.f) : v;
        }
    }

    float* dst = (mat == 0) ? zsrc : (mat == 1) ? ztgt : msg;
    #pragma unroll
    for (int bb = 0; bb < 4; ++bb) {
        float* o = dst + (size_t)(n0 + j * 4 + bb) * 64 + i * 8;
        *(float4*)o       = make_float4(acc[0][bb], acc[1][bb], acc[2][bb], acc[3][bb]);
        *(float4*)(o + 4) = make_float4(acc[4][bb], acc[5][bb], acc[6][bb], acc[7][bb]);
    }
}

// ---------------------------------------------------------------------------
// B: scorer. Exact 3-way-split bf16 MFMA, one node-pair per wave (R13
//    structure) + W2 fragments PINNED in registers via opaque asm
//    redefinition (compiler cannot remat from LDS) -> LDS pipe unloaded:
//    32 -> 4 ds_read_b128 per Mt.
// ---------------------------------------------------------------------------
__global__ __launch_bounds__(256, 3) void score_k(
    const float* __restrict__ zsrc, const float* __restrict__ ztgt,
    const float* __restrict__ zpos, const float* __restrict__ W2,
    const float* __restrict__ b2, const float* __restrict__ W3,
    const float* __restrict__ b3, float* __restrict__ scores)
{
    __shared__ fragcast fraglds[64 * 13];   // 13 KB, lane-major stride 13
    __shared__ float zpl[24 * 68];          // 6.5 KB, padded rows

    const int t = threadIdx.x;
    const int l = t & 63;
    const int lcol = l & 15;
    const int lgrp = l >> 4;
    const int w = t >> 6;
    const int wave = blockIdx.x * 4 + w;    // 16384 waves x 1 node-pair

    // stage zpos (coalesced)
    #pragma unroll
    for (int r = 0; r < 6; ++r) {
        int idx = r * 256 + t;
        zpl[(idx >> 6) * 68 + (idx & 63)] = zpos[idx];
    }
    // W2 fragments: wave w builds quadrant (jt = w>>1, kt = w&1)
    {
        const int jt = w >> 1, kt = w & 1;
        fragcast fh, fl, fl2;
        const float* wr = W2 + (size_t)(jt * 16 + lcol) * 64 + kt * 32 + lgrp * 8;
        #pragma unroll
        for (int d = 0; d < 4; ++d) {
            unsigned h0, l0, m0, h1, l1, m1;
            split3(wr[2 * d],     h0, l0, m0);
            split3(wr[2 * d + 1], h1, l1, m1);
            fh.u[d]  = pack_hi16(h0, h1);
            fl.u[d]  = pack_hi16(l0, l1);
            fl2.u[d] = pack_hi16(m0, m1);
        }
        fraglds[l * 13 + 0 + jt * 2 + kt] = fh;
        fraglds[l * 13 + 4 + jt * 2 + kt] = fl;
        fraglds[l * 13 + 8 + jt * 2 + kt] = fl2;
    }
    __syncthreads();

    // One-time fragment load, then PIN in registers: the empty asm
    // "redefines" each value, so the compiler cannot rematerialize the
    // LDS read inside the loop. 48 VGPRs, loop-invariant.
    fragcast F[12];
    #pragma unroll
    for (int i = 0; i < 12; ++i) F[i] = fraglds[l * 13 + i];
    #pragma unroll
    for (int i = 0; i < 12; ++i)
        asm volatile("" : "+v"(F[i].u));

    const f32x4 b2l0 = *(const f32x4*)(b2 + lgrp * 4);
    const f32x4 b2l1 = *(const f32x4*)(b2 + 16 + lgrp * 4);
    const f32x4 w3l0 = *(const f32x4*)(W3 + lgrp * 4);
    const f32x4 w3l1 = *(const f32x4*)(W3 + 16 + lgrp * 4);
    const float b3s = b3[0];

    const int node0 = wave * 2;

    #pragma unroll
    for (int Mt = 0; Mt < 3; ++Mt) {
        const int ke = Mt * 16 + lcol;
        const int nsel = (ke >= 24) ? 1 : 0;
        const int node = node0 + nsel;
        const int k = ke - 24 * nsel;
        const int bb = node >> 14;
        const int nl = node & (NNODES - 1);
        const int yy = nl >> 7, xx = nl & 127;
        const int kk = k + (k >= 12 ? 1 : 0);
        const int q5 = (kk * 52) >> 8;
        const int dy = q5 - 2, dx = kk - 5 * q5 - 2;
        const int ny = min(max(yy + dy, 0), 127);
        const int nx = min(max(xx + dx, 0), 127);
        const int nbn = (bb << 14) + (ny << 7) + nx;

        const float* zs = zsrc + (size_t)node * 64 + lgrp * 8;
        const float* zt = ztgt + (size_t)nbn * 64 + lgrp * 8;
        const float* zp = &zpl[k * 68 + lgrp * 8];

        f32x4 ac0A = {0.f,0.f,0.f,0.f}, ac0B = {0.f,0.f,0.f,0.f};
        f32x4 ac1A = {0.f,0.f,0.f,0.f}, ac1B = {0.f,0.f,0.f,0.f};

        #pragma unroll
        for (int kt = 0; kt < 2; ++kt) {
            const int o = kt * 32;
            float4 a0 = *(const float4*)(zs + o);
            float4 a1 = *(const float4*)(zs + o + 4);
            float4 t0 = *(const float4*)(zt + o);
            float4 t1 = *(const float4*)(zt + o + 4);
            float4 p0 = *(const float4*)(zp + o);
            float4 p1 = *(const float4*)(zp + o + 4);
            float v[8];
            v[0] = fmaxf(a0.x + t0.x + p0.x, 0.f);
            v[1] = fmaxf(a0.y + t0.y + p0.y, 0.f);
            v[2] = fmaxf(a0.z + t0.z + p0.z, 0.f);
            v[3] = fmaxf(a0.w + t0.w + p0.w, 0.f);
            v[4] = fmaxf(a1.x + t1.x + p1.x, 0.f);
            v[5] = fmaxf(a1.y + t1.y + p1.y, 0.f);
            v[6] = fmaxf(a1.z + t1.z + p1.z, 0.f);
            v[7] = fmaxf(a1.w + t1.w + p1.w, 0.f);

            fragcast Bh, Bl, Bl2;
            #pragma unroll
            for (int d = 0; d < 4; ++d) {
                unsigned h0, l0, m0, h1, l1, m1;
                split3(v[2 * d],     h0, l0, m0);
                split3(v[2 * d + 1], h1, l1, m1);
                Bh.u[d]  = pack_hi16(h0, h1);
                Bl.u[d]  = pack_hi16(l0, l1);
                Bl2.u[d] = pack_hi16(m0, m1);
            }

            ac0A = __builtin_amdgcn_mfma_f32_16x16x32_bf16(F[0 + kt].b,  Bh.b,  ac0A, 0, 0, 0);
            ac1A = __builtin_amdgcn_mfma_f32_16x16x32_bf16(F[2 + kt].b,  Bh.b,  ac1A, 0, 0, 0);
            ac0B = __builtin_amdgcn_mfma_f32_16x16x32_bf16(F[4 + kt].b,  Bh.b,  ac0B, 0, 0, 0);
            ac1B = __builtin_amdgcn_mfma_f32_16x16x32_bf16(F[6 + kt].b,  Bh.b,  ac1B, 0, 0, 0);
            ac0A = __builtin_amdgcn_mfma_f32_16x16x32_bf16(F[8 + kt].b,  Bh.b,  ac0A, 0, 0, 0);
            ac1A = __builtin_amdgcn_mfma_f32_16x16x32_bf16(F[10 + kt].b, Bh.b,  ac1A, 0, 0, 0);
            ac0B = __builtin_amdgcn_mfma_f32_16x16x32_bf16(F[0 + kt].b,  Bl.b,  ac0B, 0, 0, 0);
            ac1B = __builtin_amdgcn_mfma_f32_16x16x32_bf16(F[2 + kt].b,  Bl.b,  ac1B, 0, 0, 0);
            ac0A = __builtin_amdgcn_mfma_f32_16x16x32_bf16(F[4 + kt].b,  Bl.b,  ac0A, 0, 0, 0);
            ac1A = __builtin_amdgcn_mfma_f32_16x16x32_bf16(F[6 + kt].b,  Bl.b,  ac1A, 0, 0, 0);
            ac0B = __builtin_amdgcn_mfma_f32_16x16x32_bf16(F[0 + kt].b,  Bl2.b, ac0B, 0, 0, 0);
            ac1B = __builtin_amdgcn_mfma_f32_16x16x32_bf16(F[2 + kt].b,  Bl2.b, ac1B, 0, 0, 0);
        }

        const f32x4 s0 = ac0A + ac0B;
        const f32x4 s1 = ac1A + ac1B;
        float sacc = 0.f;
        #pragma unroll
        for (int q = 0; q < 4; ++q) {
            sacc = fmaf(fmaxf(s0[q] + b2l0[q], 0.f), w3l0[q], sacc);
            sacc = fmaf(fmaxf(s1[q] + b2l1[q], 0.f), w3l1[q], sacc);
        }
        sacc += __shfl_xor(sacc, 16);
        sacc += __shfl_xor(sacc, 32);
        float sig = 1.f / (1.f + expf(-(sacc + b3s)));
        if (l < 16)
            scores[(size_t)node0 * 24 + Mt * 16 + l] = sig;
    }
}

// ---------------------------------------------------------------------------
// C: per-node rank/mask/weights + weighted msg aggregation + Wo + residual.
// ---------------------------------------------------------------------------
__global__ __launch_bounds__(256) void agg_k(
    const float* __restrict__ x, const float* __restrict__ scores,
    const float* __restrict__ msg, const float* __restrict__ Wo,
    const float* __restrict__ bo, const float* __restrict__ thrp,
    float* __restrict__ out)
{
    __shared__ float sc[768];
    __shared__ float wl[768];
    __shared__ float sumw[32];
    __shared__ float aggL[32][64];
    __shared__ float ot[64][33];

    const int t = threadIdx.x;
    const int n0 = blockIdx.x * 32;
    const int b = n0 >> 14;
    const int nl0 = n0 & (NNODES - 1);
    const float thr_v = 1.f / (1.f + expf(-thrp[0]));

    #pragma unroll
    for (int rep = 0; rep < 3; ++rep)
        sc[rep * 256 + t] = scores[(size_t)n0 * 24 + rep * 256 + t];
    __syncthreads();

    #pragma unroll
    for (int rep = 0; rep < 3; ++rep) {
        int e = rep * 256 + t;
        int nl = (int)(((unsigned)(e >> 3) * 171u) >> 9);   // e/24 for e<768
        int k = e - nl * 24;
        float s_e = sc[e];
        int rank = 0, cnt = 0;
        #pragma unroll
        for (int j = 0; j < 24; ++j) {
            float sj = sc[nl * 24 + j];
            rank += (sj > s_e || (sj == s_e && j < k)) ? 1 : 0;
            cnt  += (sj >= thr_v) ? 1 : 0;
        }
        bool mask = (cnt > 8) ? (rank < 8)
                  : ((cnt < 3) ? (rank < 3) : (s_e >= thr_v));
        float keep = 1.f / (1.f + expf(-(s_e - thr_v) * 10.f));
        wl[e] = mask ? s_e * keep : 0.f;
    }
    __syncthreads();

    if (t < 32) {
        float s = 0.f;
        #pragma unroll
        for (int k = 0; k < 24; ++k) s += wl[t * 24 + k];
        sumw[t] = s + 1e-6f;
    }
    __syncthreads();

    const int lane = t & 63;
    const int g4 = t >> 6;

    #pragma unroll
    for (int it = 0; it < 8; ++it) {
        int nl = g4 + it * 4;
        int nn = nl0 + nl;
        int yy = nn >> 7, xx = nn & 127;
        float acc = 0.f;
        #pragma unroll
        for (int k = 0; k < 24; ++k) {
            int kk = k + (k >= 12 ? 1 : 0);
            int q5 = (kk * 52) >> 8;
            int dy = q5 - 2, dx = kk - 5 * q5 - 2;
            int ny = min(max(yy + dy, 0), 127);
            int nx = min(max(xx + dx, 0), 127);
            int nb = (b << 14) + (ny << 7) + nx;
            acc = fmaf(wl[nl * 24 + k], msg[(size_t)nb * 64 + lane], acc);
        }
        aggL[nl][lane] = acc / sumw[nl];
    }

    float4 wo[16];
    #pragma unroll
    for (int c4 = 0; c4 < 16; ++c4) wo[c4] = ((const float4*)Wo)[lane * 16 + c4];
    __syncthreads();

    #pragma unroll
    for (int it = 0; it < 8; ++it) {
        int nl = g4 + it * 4;
        const float4* ar = (const float4*)aggL[nl];
        float a0 = 0.f, a1 = 0.f, a2 = 0.f, a3 = 0.f;
        #pragma unroll
        for (int c4 = 0; c4 < 16; ++c4) {
            float4 wv = wo[c4];
            float4 av = ar[c4];
            a0 = fmaf(av.x, wv.x, a0);
            a1 = fmaf(av.y, wv.y, a1);
            a2 = fmaf(av.z, wv.z, a2);
            a3 = fmaf(av.w, wv.w, a3);
        }
        float v = (a0 + a1) + (a2 + a3) + bo[lane]
                + x[(size_t)b * 64 * NNODES + (size_t)lane * NNODES + nl0 + nl];
        ot[lane][nl] = v;
    }
    __syncthreads();

    #pragma unroll
    for (int rep = 0; rep < 2; ++rep) {
        int idx = rep * 256 + t;
        int o = idx >> 3, p = idx & 7;
        float4 v = make_float4(ot[o][4 * p + 0], ot[o][4 * p + 1],
                               ot[o][4 * p + 2], ot[o][4 * p + 3]);
        *(float4*)(out + (size_t)b * 64 * NNODES + (size_t)o * NNODES + nl0 + 4 * p) = v;
    }
}

// ---------------------------------------------------------------------------
extern "C" void kernel_launch(void* const* d_in, const int* in_sizes, int n_in,
                              void* d_out, int out_size, void* d_ws, size_t ws_size,
                              hipStream_t stream)
{
    const float* x   = (const float*)d_in[0];
    const float* W1  = (const float*)d_in[1];
    const float* b1  = (const float*)d_in[2];
    const float* W2  = (const float*)d_in[3];
    const float* b2  = (const float*)d_in[4];
    const float* W3  = (const float*)d_in[5];
    const float* b3  = (const float*)d_in[6];
    const float* thr = (const float*)d_in[7];
    const float* Wm  = (const float*)d_in[8];
    const float* bm  = (const float*)d_in[9];
    const float* Wo  = (const float*)d_in[10];
    const float* bo  = (const float*)d_in[11];
    float* out = (float*)d_out;
    float* ws  = (float*)d_ws;

    // ws layout (floats): zsrc[2M] ztgt[2M] msg[2M] scores[768K] zpos[1536]
    float* zsrc   = ws;
    float* ztgt   = ws + 2097152;
    float* msg    = ws + 4194304;
    float* scores = ws + 6291456;
    float* zpos   = ws + 7077888;

    hipLaunchKernelGGL(precompute_k, dim3(768), dim3(256), 0, stream,
                       x, W1, Wm, b1, bm, zsrc, ztgt, msg, zpos);
    hipLaunchKernelGGL(score_k, dim3(4096), dim3(256), 0, stream,
                       zsrc, ztgt, zpos, W2, b2, W3, b3, scores);
    hipLaunchKernelGGL(agg_k, dim3(1024), dim3(256), 0, stream,
                       x, scores, msg, Wo, bo, thr, out);
}